// Round 10
// baseline (910.925 us; speedup 1.0000x reference)
//
#include <hip/hip_runtime.h>
#include <hip/hip_bf16.h>

#define B_ 4
#define P_ 12000
#define N_ 32
#define H1_ 666
#define W1_ 666
#define HW1 (H1_*W1_)
#define H2_ 333
#define W2_ 333
#define HW2 (H2_*W2_)
#define H3_ 166
#define W3_ 166
#define HW3 (H3_*W3_)
#define EPS_ 1e-5f

// padded channels-last buffer dims
#define PSH_H 340
#define PSH_W 708
#define P1_H 340
#define P1_W 388
#define P2_H 172
#define P2_W 196

typedef short s16x8 __attribute__((ext_vector_type(8)));
typedef float f32x4 __attribute__((ext_vector_type(4)));

__device__ __forceinline__ unsigned short f2bf(float f) {
    unsigned int x = __float_as_uint(f);
    return (unsigned short)((x + 0x7fffu + ((x >> 16) & 1u)) >> 16);
}
__device__ __forceinline__ float bf2f(unsigned short u) {
    return __uint_as_float(((unsigned int)u) << 16);
}

__device__ __forceinline__ void gload16(const void* g, void* l) {
    __builtin_amdgcn_global_load_lds(
        (const __attribute__((address_space(1))) void*)g,
        (__attribute__((address_space(3))) void*)l, 16, 0, 0);
}

// ---------------- diagnostic fill ----------------
__global__ void k_diag(float* __restrict__ out, int n, float val) {
    int i = blockIdx.x * 256 + threadIdx.x;
    if (i < n) out[i] = val;
}

// ---------------- fused pillar linear + BN0 stats + max over N ----------------
__global__ __launch_bounds__(256) void k_linmax(
    const float* __restrict__ pillars,
    const float* __restrict__ lin_w, const float* __restrict__ lin_b,
    float* __restrict__ maxx, float* __restrict__ sbuf) {
    __shared__ float xs[64 * 268];
    __shared__ float wsm[64 * 10];
    const int tid = threadIdx.x;
    if (tid < 64) {
#pragma unroll
        for (int j = 0; j < 9; ++j) wsm[tid * 10 + j] = lin_w[tid * 9 + j];
        wsm[tid * 10 + 9] = lin_b[tid];
    }
    __syncthreads();
    const float* p = pillars + (size_t)(blockIdx.x * 256 + tid) * 9;
    float f0=p[0], f1=p[1], f2=p[2], f3=p[3], f4=p[4],
          f5=p[5], f6=p[6], f7=p[7], f8=p[8];
#pragma unroll
    for (int c = 0; c < 64; ++c) {
        const float* wc = &wsm[c * 10];
        float x = wc[9] + wc[0]*f0 + wc[1]*f1 + wc[2]*f2 + wc[3]*f3 + wc[4]*f4
                        + wc[5]*f5 + wc[6]*f6 + wc[7]*f7 + wc[8]*f8;
        xs[c * 268 + tid] = x;
    }
    __syncthreads();
    const int c = tid & 63;
    const int w = tid >> 6;
    float s = 0.f, q = 0.f;
#pragma unroll
    for (int pi = 0; pi < 2; ++pi) {
        const int pp = w + pi * 4;
        float mx = -3e38f;
#pragma unroll
        for (int j = 0; j < 32; j += 4) {
            f32x4 v = *(const f32x4*)&xs[c * 268 + pp * 32 + j];
            s += v[0] + v[1] + v[2] + v[3];
            q += v[0]*v[0] + v[1]*v[1] + v[2]*v[2] + v[3]*v[3];
            mx = fmaxf(mx, fmaxf(fmaxf(v[0], v[1]), fmaxf(v[2], v[3])));
        }
        maxx[(size_t)(blockIdx.x * 8 + pp) * 64 + c] = mx;
    }
    float* mybuf = sbuf + (size_t)(blockIdx.x & 63) * 128;
    atomicAdd(&mybuf[c], s);
    atomicAdd(&mybuf[64 + c], q);
}

// ---------------- BN finalize from 64 contention buffers ----------------
__global__ void k_finalize2(const float* __restrict__ bufs,
                            const float* __restrict__ g, const float* __restrict__ b,
                            float* __restrict__ scale, float* __restrict__ shift,
                            int C, float invN) {
    int c = blockIdx.x * 256 + threadIdx.x;
    if (c >= C) return;
    float s = 0.f, q = 0.f;
    for (int k = 0; k < 64; ++k) {
        s += bufs[(size_t)k * 2 * C + c];
        q += bufs[(size_t)k * 2 * C + C + c];
    }
    float m = s * invN;
    float v = q * invN - m * m;
    float sc = g[c] * rsqrtf(v + EPS_);
    scale[c] = sc;
    shift[c] = b[c] - m * sc;
}

// ---------------- feats = bf16(relu(bn(maxx))) ----------------
__global__ void k_featsbn(const float* __restrict__ maxx,
                          const float* __restrict__ sc, const float* __restrict__ sh,
                          short* __restrict__ feats) {
    int i = blockIdx.x * 256 + threadIdx.x;
    if (i >= B_ * P_ * 8) return;
    int c0 = (i & 7) * 8;
    size_t base = (size_t)(i >> 3) * 64 + c0;
    f32x4 v0 = *(const f32x4*)&maxx[base];
    f32x4 v1 = *(const f32x4*)&maxx[base + 4];
    ushort4 o0, o1;
    o0.x = f2bf(fmaxf(fmaf(v0[0], sc[c0+0], sh[c0+0]), 0.f));
    o0.y = f2bf(fmaxf(fmaf(v0[1], sc[c0+1], sh[c0+1]), 0.f));
    o0.z = f2bf(fmaxf(fmaf(v0[2], sc[c0+2], sh[c0+2]), 0.f));
    o0.w = f2bf(fmaxf(fmaf(v0[3], sc[c0+3], sh[c0+3]), 0.f));
    o1.x = f2bf(fmaxf(fmaf(v1[0], sc[c0+4], sh[c0+4]), 0.f));
    o1.y = f2bf(fmaxf(fmaf(v1[1], sc[c0+5], sh[c0+5]), 0.f));
    o1.z = f2bf(fmaxf(fmaf(v1[2], sc[c0+6], sh[c0+6]), 0.f));
    o1.w = f2bf(fmaxf(fmaf(v1[3], sc[c0+7], sh[c0+7]), 0.f));
    *(ushort4*)&feats[base] = o0;
    *(ushort4*)&feats[base + 4] = o1;
}

// ---------------- coords dtype probe ----------------
__global__ void k_probe_coords(const int* __restrict__ c32, int* __restrict__ flag) {
    int nz = 0;
    for (int i = 0; i < 512; ++i) nz |= c32[2*i + 1];
    *flag = (nz == 0) ? 1 : 0;
}

// ---- weight transform: f32 [Cout][Cin][3][3] -> bf16 frag order, bank-swizzled
__global__ void k_wt2(const float* __restrict__ src, short* __restrict__ dst,
                      int Cin, int MT, int NCB, int total) {
    int i = blockIdx.x * 256 + threadIdx.x;
    if (i >= total) return;
    int e = i & 7;  int t = i >> 3;
    int chunk = t & 63; t >>= 6;
    int n16 = chunk >> 2;
    int g = (chunk & 3) ^ ((n16 >> 1) & 3);
    int mt = t % MT;  t /= MT;
    int tap = t % 9;  t /= 9;
    int cb = t % NCB; int cg = t / NCB;
    int co = (cg * MT + mt) * 16 + n16;
    int ci = cb * 32 + g * 8 + e;
    dst[i] = (short)f2bf(src[((size_t)co * Cin + ci) * 9 + tap]);
}

__global__ void k_wt2_heads(const float* __restrict__ box, const float* __restrict__ cls,
                            const float* __restrict__ dir,
                            const float* __restrict__ boxb, const float* __restrict__ clsb,
                            const float* __restrict__ dirb,
                            short* __restrict__ dst, float* __restrict__ bias) {
    int i = blockIdx.x * 256 + threadIdx.x;      // 8cb*9*2*64chunks*8 = 73728
    if (i >= 73728) return;
    int e = i & 7;  int t = i >> 3;
    int chunk = t & 63; t >>= 6;
    int n16 = chunk >> 2;
    int g = (chunk & 3) ^ ((n16 >> 1) & 3);
    int mt = t & 1;   t >>= 1;
    int tap = t % 9;  int cb = t / 9;
    int oc = mt * 16 + n16;
    int ci = cb * 32 + g * 8 + e;
    float v = 0.f;
    if (oc < 21)      v = box[((size_t)oc * 256 + ci) * 9 + tap];
    else if (oc < 24) v = cls[((size_t)(oc - 21) * 256 + ci) * 9 + tap];
    else if (oc < 26) v = dir[((size_t)(oc - 24) * 256 + ci) * 9 + tap];
    dst[i] = (short)f2bf(v);
    if (i < 32) {
        float bv = 0.f;
        if (i < 21) bv = boxb[i];
        else if (i < 24) bv = clsb[i - 21];
        else if (i < 26) bv = dirb[i - 24];
        bias[i] = bv;
    }
}

// ---------------- scatter feats (or zeros) into padded half pseudo-image ----
template<bool CLEAR>
__global__ void k_scatter(const short* __restrict__ feats,
                          const int* __restrict__ coords32,
                          const int* __restrict__ flag64,
                          short* __restrict__ pseudo,
                          int b, int ylo, int yhi, int rowOff) {
    const int p = blockIdx.x * 4 + (threadIdx.x >> 6);
    const int c = threadIdx.x & 63;
    const int bp = b * P_ + p;
    long long y, x;
    if (*flag64) {
        const long long* c64 = (const long long*)coords32;
        y = c64[(size_t)bp*4 + 1];
        x = c64[(size_t)bp*4 + 2];
    } else {
        y = coords32[(size_t)bp*4 + 1];
        x = coords32[(size_t)bp*4 + 2];
    }
    if (y >= ylo && y < yhi && x >= 0 && x < W1_)
        pseudo[(((size_t)(y - 1 - rowOff + 1)) * PSH_W + (x + 1)) * 64 + c]
            = CLEAR ? (short)0 : feats[(size_t)bp * 64 + c];
}

// ---------------- bn + relu in place over padded interior ----------------
template<int C>
__global__ void k_bnrelu_pad(short* __restrict__ buf,
                             const float* __restrict__ sc, const float* __restrict__ sh,
                             int Hd, int Wd, int Hp, int Wp) {
    constexpr int OCT = C / 8;
    constexpr int LO = (C == 64) ? 3 : (C == 128) ? 4 : 5;
    size_t i = (size_t)blockIdx.x * 256 + threadIdx.x;
    size_t total = (size_t)B_ * Hd * Wd * OCT;
    if (i >= total) return;
    int oct = (int)(i & (OCT - 1));
    size_t t = i >> LO;
    int x = (int)(t % Wd); t /= Wd;
    int y = (int)(t % Hd);
    int b = (int)(t / Hd);
    size_t idx = (((size_t)b * Hp + y + 1) * Wp + x + 1) * C + oct * 8;
    uint4 v = *(uint4*)&buf[idx];
    unsigned short* u = (unsigned short*)&v;
#pragma unroll
    for (int j = 0; j < 8; ++j)
        u[j] = f2bf(fmaxf(fmaf(bf2f(u[j]), sc[oct*8 + j], sh[oct*8 + j]), 0.f));
    *(uint4*)&buf[idx] = v;
}

// ---------------- MFMA tap-GEMM conv3x3, R=4, double-buffered pipeline ------
// 2-phase: issue next cb-slice's global_load_lds BEFORE computing current;
// the per-slice __syncthreads (implicit vmcnt drain) lands after compute.
template<int CIN, int MT, bool POOL, bool STATS, bool HEADS>
__global__ __launch_bounds__(256) void k_mconv4(
    const short* __restrict__ in, const short* __restrict__ wt2,
    const float* __restrict__ bias,
    short* __restrict__ out, float* __restrict__ outf,
    float* __restrict__ sbuf,
    int Hp, int Wp, int rowOff, int yoff,
    int Win, int Hin, int HpO, int WpO, int CoutT, int cgCount) {

    constexpr int NCB = CIN / 32;
    constexpr int ACH = 9 * MT * 64;             // A 16B chunks per cb slice
    constexpr int BCH = 6 * 66 * 4;              // B 16B chunks per cb slice
    __shared__ short sA[2][ACH * 8];
    __shared__ short sB[2][BCH * 8];

    const int tid = threadIdx.x;
    const int lane = tid & 63, w = tid >> 6;
    const int n16 = lane & 15, g = lane >> 4;
    const int b  = blockIdx.z / cgCount;
    const int cg = blockIdx.z % cgCount;
    const int co0 = cg * (MT * 16);
    const int byp = blockIdx.y + yoff;
    const int cy0 = 4 * byp;
    const int x0 = blockIdx.x * 64;
    const int r0p = cy0 - 1 - rowOff;
    const int colbase = w * 16 + n16;
    const int xg = x0 + colbase;

    const short* awBase = wt2 + (size_t)cg * NCB * ACH * 8;
    const short* bwBase = in + (((size_t)b * Hp + r0p) * Wp + x0) * CIN;

    auto stage = [&](int bufi, int cbi) {
        const short* aw = awBase + (size_t)cbi * ACH * 8;
#pragma unroll
        for (int cc0 = 0; cc0 < ACH; cc0 += 256) {
            int ch = cc0 + tid;
            if (ch < ACH)
                gload16(aw + (size_t)ch * 8, &sA[bufi][(cc0 + w * 64) * 8]);
        }
        const short* bw = bwBase + cbi * 32;
#pragma unroll
        for (int cc0 = 0; cc0 < BCH; cc0 += 256) {
            int ch = cc0 + tid;
            if (ch < BCH) {
                int oslot = ch & 3;
                int col = (ch >> 2) % 66;
                int row = ch / 264;
                int oct = oslot ^ ((col >> 1) & 3);
                gload16(bw + ((size_t)row * Wp + col) * CIN + oct * 8,
                        &sB[bufi][(cc0 + w * 64) * 8]);
            }
        }
    };

    // conflict-free chunk offsets
    const int aoff = n16 * 4 + (g ^ ((n16 >> 1) & 3));
    int boff[3];
#pragma unroll
    for (int dx = 0; dx < 3; ++dx) {
        int cdx = colbase + dx;
        boff[dx] = cdx * 4 + (g ^ ((cdx >> 1) & 3));
    }

    f32x4 acc[4][MT];
#pragma unroll
    for (int r = 0; r < 4; ++r)
#pragma unroll
        for (int mt = 0; mt < MT; ++mt)
            acc[r][mt] = *(const f32x4*)&bias[co0 + mt * 16 + g * 4];

    stage(0, 0);
    __syncthreads();

    for (int cb = 0; cb < NCB; ++cb) {
        const int cur = cb & 1;
        if (cb + 1 < NCB) stage(cur ^ 1, cb + 1);
#pragma unroll
        for (int tap = 0; tap < 9; ++tap) {
            const int dy = tap / 3, dx = tap % 3;
            s16x8 a[MT], bf[4];
#pragma unroll
            for (int mt = 0; mt < MT; ++mt)
                a[mt] = *(const s16x8*)&sA[cur][((tap * MT + mt) * 64 + aoff) * 8];
#pragma unroll
            for (int r = 0; r < 4; ++r)
                bf[r] = *(const s16x8*)&sB[cur][((r + dy) * 264 + boff[dx]) * 8];
#pragma unroll
            for (int r = 0; r < 4; ++r)
#pragma unroll
                for (int mt = 0; mt < MT; ++mt)
                    acc[r][mt] = __builtin_amdgcn_mfma_f32_16x16x32_bf16(
                        a[mt], bf[r], acc[r][mt], 0, 0, 0);
        }
        __syncthreads();
    }

    if (STATS) {
        const bool colok = xg < Win;
        float* mybuf = sbuf + (size_t)((blockIdx.x + blockIdx.y) & 63) * (2 * CoutT);
#pragma unroll
        for (int mt = 0; mt < MT; ++mt) {
#pragma unroll
            for (int reg = 0; reg < 4; ++reg) {
                float sv = 0.f, qv = 0.f;
                if (colok) {
#pragma unroll
                    for (int r = 0; r < 4; ++r) {
                        if (cy0 + r < Hin) {
                            float v = acc[r][mt][reg];
                            sv += v; qv += v * v;
                        }
                    }
                }
#pragma unroll
                for (int o = 1; o < 16; o <<= 1) {
                    sv += __shfl_xor(sv, o);
                    qv += __shfl_xor(qv, o);
                }
                if (n16 == 0) {
                    int c = co0 + mt * 16 + g * 4 + reg;
                    atomicAdd(&mybuf[c], sv);
                    atomicAdd(&mybuf[CoutT + c], qv);
                }
            }
        }
    }

    if (HEADS) {
        if (xg < Win) {
#pragma unroll
            for (int r = 0; r < 4; ++r) {
                if (cy0 + r >= Hin) continue;
#pragma unroll
                for (int mt = 0; mt < MT; ++mt)
#pragma unroll
                    for (int reg = 0; reg < 4; ++reg) {
                        int oc = co0 + mt * 16 + g * 4 + reg;
                        float v = acc[r][mt][reg];
                        size_t px = (size_t)(cy0 + r) * W3_ + xg;
                        if (oc < 21)
                            outf[((size_t)(b * 21 + oc)) * HW3 + px] = v;
                        else if (oc < 24)
                            outf[(size_t)4 * 21 * HW3 + ((size_t)(b * 3 + oc - 21)) * HW3 + px] = v;
                        else if (oc < 26)
                            outf[(size_t)4 * 24 * HW3 + ((size_t)(b * 2 + oc - 24)) * HW3 + px] = v;
                    }
            }
        }
    } else if (POOL) {
        const bool colok = ((n16 & 1) == 0) && (xg + 1 < Win);
#pragma unroll
        for (int k = 0; k < 2; ++k) {
            const int py = 2 * byp + k;
            const bool rowok = (2 * py + 1 < Hin);
#pragma unroll
            for (int mt = 0; mt < MT; ++mt) {
                float pv[4];
#pragma unroll
                for (int reg = 0; reg < 4; ++reg) {
                    float v = fmaxf(acc[2*k][mt][reg], acc[2*k+1][mt][reg]);
                    v = fmaxf(v, __shfl_xor(v, 1));
                    pv[reg] = v;
                }
                if (colok && rowok) {
                    size_t o = (((size_t)b * HpO + py + 1) * WpO + (xg >> 1) + 1) * CoutT
                               + co0 + mt * 16 + g * 4;
                    ushort4 pk = { f2bf(pv[0]), f2bf(pv[1]), f2bf(pv[2]), f2bf(pv[3]) };
                    *(ushort4*)&out[o] = pk;
                }
            }
        }
    } else {
        if (xg < Win) {
#pragma unroll
            for (int r = 0; r < 4; ++r) {
                if (cy0 + r >= Hin) continue;
#pragma unroll
                for (int mt = 0; mt < MT; ++mt) {
                    size_t o = (((size_t)b * HpO + cy0 + r + 1) * WpO + xg + 1) * CoutT
                               + co0 + mt * 16 + g * 4;
                    ushort4 pk = { f2bf(acc[r][mt][0]), f2bf(acc[r][mt][1]),
                                   f2bf(acc[r][mt][2]), f2bf(acc[r][mt][3]) };
                    *(ushort4*)&out[o] = pk;
                }
            }
        }
    }
}

extern "C" void kernel_launch(void* const* d_in, const int* in_sizes, int n_in,
                              void* d_out, int out_size, void* d_ws, size_t ws_size,
                              hipStream_t stream) {
    const float* pillars = (const float*)d_in[0];
    const int*   coords  = (const int*)d_in[1];
    const float* lin_w = (const float*)d_in[2];
    const float* lin_b = (const float*)d_in[3];
    const float* bn0_g = (const float*)d_in[4];
    const float* bn0_b = (const float*)d_in[5];
    const float* c1_w  = (const float*)d_in[6];
    const float* c1_b  = (const float*)d_in[7];
    const float* bn1_g = (const float*)d_in[8];
    const float* bn1_b = (const float*)d_in[9];
    const float* c2_w  = (const float*)d_in[10];
    const float* c2_b  = (const float*)d_in[11];
    const float* bn2_g = (const float*)d_in[12];
    const float* bn2_b = (const float*)d_in[13];
    const float* h1_w  = (const float*)d_in[14];
    const float* h1_b  = (const float*)d_in[15];
    const float* hbn_g = (const float*)d_in[16];
    const float* hbn_b = (const float*)d_in[17];
    const float* box_w = (const float*)d_in[18];
    const float* box_b = (const float*)d_in[19];
    const float* cls_w = (const float*)d_in[20];
    const float* cls_b = (const float*)d_in[21];
    const float* dir_w = (const float*)d_in[22];
    const float* dir_b = (const float*)d_in[23];

    // ---- workspace layout ----
    const size_t szPseudo = (size_t)PSH_H * PSH_W * 64 * 2;
    const size_t szP1  = (size_t)B_ * P1_H * P1_W * 64 * 2;
    const size_t szP2  = (size_t)B_ * P2_H * P2_W * 128 * 2;
    const size_t szH1p = (size_t)B_ * P2_H * P2_W * 256 * 2;
    const size_t szR1 = szH1p;
    const size_t szR2 = szP2;
    const size_t offR1 = 0;
    const size_t offR2 = szR1;
    const size_t offFeats = offR2 + szR2;
    const size_t szFeats = (size_t)B_ * P_ * 64 * 2;
    const size_t offC1W = offFeats + szFeats;
    const size_t offC2W = offC1W + 73728;
    const size_t offH1W = offC2W + 147456;
    const size_t offHDW = offH1W + 589824;
    const size_t offArena = offHDW + 147456;
    const size_t wsNeeded = offArena + 300000;
    char* ws = (char*)d_ws;

    if (ws_size < wsNeeded) {
        float mb = (float)(double)(ws_size >> 20);
        k_diag<<<(out_size + 255) / 256, 256, 0, stream>>>((float*)d_out, out_size, mb);
        return;
    }

    float* F = (float*)(ws + offArena);
    float* sbuf0 = F;
    float* L1buf = F + 8192;
    float* L2buf = F + 16384;
    float* L3buf = F + 32768;
    float* sc0 = F + 65536; float* sh0 = F + 65600;
    float* sc1 = F + 65664; float* sh1 = F + 65728;
    float* sc2 = F + 65792; float* sh2 = F + 65920;
    float* sc3 = F + 66048; float* sh3 = F + 66304;
    float* hdbias = F + 66560;
    int* flag64 = (int*)(F + 66596);

    short* pooled1 = (short*)(ws + offR1);
    short* h1p     = (short*)(ws + offR1);
    float* maxx    = (float*)(ws + offR2);
    short* pseudo  = (short*)(ws + offR2);
    short* pooled2 = (short*)(ws + offR2);
    short* feats   = (short*)(ws + offFeats);
    short* c1wt = (short*)(ws + offC1W);
    short* c2wt = (short*)(ws + offC2W);
    short* h1wt = (short*)(ws + offH1W);
    short* hdwt = (short*)(ws + offHDW);

    hipMemsetAsync(ws + offArena, 0, 262144, stream);
    hipMemsetAsync(ws + offR1, 0, szP1, stream);
    k_probe_coords<<<1, 1, 0, stream>>>(coords, flag64);

    k_wt2<<<(64*64*9 + 255)/256, 256, 0, stream>>>(c1_w, c1wt, 64, 4, 2, 64*64*9);
    k_wt2<<<(128*64*9 + 255)/256, 256, 0, stream>>>(c2_w, c2wt, 64, 4, 2, 128*64*9);
    k_wt2<<<(256*128*9 + 255)/256, 256, 0, stream>>>(h1_w, h1wt, 128, 4, 4, 256*128*9);
    k_wt2_heads<<<(73728 + 255)/256, 256, 0, stream>>>(box_w, cls_w, dir_w,
                                                       box_b, cls_b, dir_b,
                                                       hdwt, hdbias);

    // pillar stage
    k_linmax<<<B_ * P_ * N_ / 256, 256, 0, stream>>>(pillars, lin_w, lin_b, maxx, sbuf0);
    k_finalize2<<<1, 64, 0, stream>>>(sbuf0, bn0_g, bn0_b, sc0, sh0, 64,
                                      1.0f / (float)(B_ * P_ * N_));
    k_featsbn<<<(B_ * P_ * 8 + 255)/256, 256, 0, stream>>>(maxx, sc0, sh0, feats);

    // conv1 (64->64 @666^2, raw pool -> pooled1), per (batch, half)
    hipMemsetAsync(pseudo, 0, szPseudo, stream);
    for (int b = 0; b < B_; ++b) {
        for (int h = 0; h < 2; ++h) {
            const int ylo = h ? 335 : 0;
            const int yhi = h ? 666 : 337;
            const int rowOff = h ? 335 : -1;
            const int yoff = h ? 84 : 0;
            const int ny = h ? 83 : 84;
            k_scatter<false><<<P_ / 4, 256, 0, stream>>>(feats, coords, flag64, pseudo,
                                                         b, ylo, yhi, rowOff);
            dim3 gr(11, ny, 1);
            k_mconv4<64, 4, true, true, false><<<gr, 256, 0, stream>>>(
                pseudo, c1wt, c1_b,
                pooled1 + (size_t)b * P1_H * P1_W * 64, nullptr, L1buf,
                PSH_H, PSH_W, rowOff, yoff, W1_, H1_, P1_H, P1_W, 64, 1);
            k_scatter<true><<<P_ / 4, 256, 0, stream>>>(feats, coords, flag64, pseudo,
                                                        b, ylo, yhi, rowOff);
        }
    }
    k_finalize2<<<1, 64, 0, stream>>>(L1buf, bn1_g, bn1_b, sc1, sh1, 64,
                                      1.0f / ((float)B_ * HW1));
    {
        size_t total = (size_t)B_ * H2_ * W2_ * 8;
        k_bnrelu_pad<64><<<(unsigned)((total + 255) / 256), 256, 0, stream>>>(
            pooled1, sc1, sh1, H2_, W2_, P1_H, P1_W);
    }

    // conv2 (64->128 @333^2, raw pool -> pooled2)
    hipMemsetAsync(ws + offR2, 0, szP2, stream);
    {
        dim3 gr(6, 84, 2 * B_);
        k_mconv4<64, 4, true, true, false><<<gr, 256, 0, stream>>>(
            pooled1, c2wt, c2_b, pooled2, nullptr, L2buf,
            P1_H, P1_W, -1, 0, W2_, H2_, P2_H, P2_W, 128, 2);
    }
    k_finalize2<<<1, 128, 0, stream>>>(L2buf, bn2_g, bn2_b, sc2, sh2, 128,
                                       1.0f / ((float)B_ * HW2));
    {
        size_t total = (size_t)B_ * H3_ * W3_ * 16;
        k_bnrelu_pad<128><<<(unsigned)((total + 255) / 256), 256, 0, stream>>>(
            pooled2, sc2, sh2, H3_, W3_, P2_H, P2_W);
    }

    // h1 (128->256 @166^2, 4 out rows/block) -> h1p raw
    hipMemsetAsync(ws + offR1, 0, szH1p, stream);
    {
        dim3 gr(3, 42, 4 * B_);
        k_mconv4<128, 4, false, true, false><<<gr, 256, 0, stream>>>(
            pooled2, h1wt, h1_b, h1p, nullptr, L3buf,
            P2_H, P2_W, -1, 0, W3_, H3_, P2_H, P2_W, 256, 4);
    }
    k_finalize2<<<1, 256, 0, stream>>>(L3buf, hbn_g, hbn_b, sc3, sh3, 256,
                                       1.0f / ((float)B_ * HW3));
    {
        size_t total = (size_t)B_ * H3_ * W3_ * 32;
        k_bnrelu_pad<256><<<(unsigned)((total + 255) / 256), 256, 0, stream>>>(
            h1p, sc3, sh3, H3_, W3_, P2_H, P2_W);
    }

    // heads: fused 26-channel conv, f32 out
    {
        dim3 gr(3, 42, B_);
        k_mconv4<256, 2, false, false, true><<<gr, 256, 0, stream>>>(
            h1p, hdwt, hdbias, nullptr, (float*)d_out, nullptr,
            P2_H, P2_W, -1, 0, W3_, H3_, P2_H, P2_W, 32, 1);
    }
}

// Round 11
// 787.214 us; speedup vs baseline: 1.1572x; 1.1572x over previous
//
#include <hip/hip_runtime.h>
#include <hip/hip_bf16.h>

#define B_ 4
#define P_ 12000
#define N_ 32
#define H1_ 666
#define W1_ 666
#define HW1 (H1_*W1_)
#define H2_ 333
#define W2_ 333
#define HW2 (H2_*W2_)
#define H3_ 166
#define W3_ 166
#define HW3 (H3_*W3_)
#define EPS_ 1e-5f

// padded channels-last buffer dims
#define PSH_H 340
#define PSH_W 708
#define P1_H 340
#define P1_W 388
#define P2_H 172
#define P2_W 196

typedef short s16x8 __attribute__((ext_vector_type(8)));
typedef float f32x4 __attribute__((ext_vector_type(4)));

__device__ __forceinline__ unsigned short f2bf(float f) {
    unsigned int x = __float_as_uint(f);
    return (unsigned short)((x + 0x7fffu + ((x >> 16) & 1u)) >> 16);
}
__device__ __forceinline__ float bf2f(unsigned short u) {
    return __uint_as_float(((unsigned int)u) << 16);
}

__device__ __forceinline__ void gload16(const void* g, void* l) {
    __builtin_amdgcn_global_load_lds(
        (const __attribute__((address_space(1))) void*)g,
        (__attribute__((address_space(3))) void*)l, 16, 0, 0);
}

// ---------------- diagnostic fill ----------------
__global__ void k_diag(float* __restrict__ out, int n, float val) {
    int i = blockIdx.x * 256 + threadIdx.x;
    if (i < n) out[i] = val;
}

// ---------------- fused pillar linear + BN0 stats + max over N ----------------
__global__ __launch_bounds__(256) void k_linmax(
    const float* __restrict__ pillars,
    const float* __restrict__ lin_w, const float* __restrict__ lin_b,
    float* __restrict__ maxx, float* __restrict__ sbuf) {
    __shared__ float xs[64 * 268];
    __shared__ float wsm[64 * 10];
    const int tid = threadIdx.x;
    if (tid < 64) {
#pragma unroll
        for (int j = 0; j < 9; ++j) wsm[tid * 10 + j] = lin_w[tid * 9 + j];
        wsm[tid * 10 + 9] = lin_b[tid];
    }
    __syncthreads();
    const float* p = pillars + (size_t)(blockIdx.x * 256 + tid) * 9;
    float f0=p[0], f1=p[1], f2=p[2], f3=p[3], f4=p[4],
          f5=p[5], f6=p[6], f7=p[7], f8=p[8];
#pragma unroll
    for (int c = 0; c < 64; ++c) {
        const float* wc = &wsm[c * 10];
        float x = wc[9] + wc[0]*f0 + wc[1]*f1 + wc[2]*f2 + wc[3]*f3 + wc[4]*f4
                        + wc[5]*f5 + wc[6]*f6 + wc[7]*f7 + wc[8]*f8;
        xs[c * 268 + tid] = x;
    }
    __syncthreads();
    const int c = tid & 63;
    const int w = tid >> 6;
    float s = 0.f, q = 0.f;
#pragma unroll
    for (int pi = 0; pi < 2; ++pi) {
        const int pp = w + pi * 4;
        float mx = -3e38f;
#pragma unroll
        for (int j = 0; j < 32; j += 4) {
            f32x4 v = *(const f32x4*)&xs[c * 268 + pp * 32 + j];
            s += v[0] + v[1] + v[2] + v[3];
            q += v[0]*v[0] + v[1]*v[1] + v[2]*v[2] + v[3]*v[3];
            mx = fmaxf(mx, fmaxf(fmaxf(v[0], v[1]), fmaxf(v[2], v[3])));
        }
        maxx[(size_t)(blockIdx.x * 8 + pp) * 64 + c] = mx;
    }
    float* mybuf = sbuf + (size_t)(blockIdx.x & 63) * 128;
    atomicAdd(&mybuf[c], s);
    atomicAdd(&mybuf[64 + c], q);
}

// ---------------- BN finalize from 64 contention buffers ----------------
__global__ void k_finalize2(const float* __restrict__ bufs,
                            const float* __restrict__ g, const float* __restrict__ b,
                            float* __restrict__ scale, float* __restrict__ shift,
                            int C, float invN) {
    int c = blockIdx.x * 256 + threadIdx.x;
    if (c >= C) return;
    float s = 0.f, q = 0.f;
    for (int k = 0; k < 64; ++k) {
        s += bufs[(size_t)k * 2 * C + c];
        q += bufs[(size_t)k * 2 * C + C + c];
    }
    float m = s * invN;
    float v = q * invN - m * m;
    float sc = g[c] * rsqrtf(v + EPS_);
    scale[c] = sc;
    shift[c] = b[c] - m * sc;
}

// ---------------- feats = bf16(relu(bn(maxx))) ----------------
__global__ void k_featsbn(const float* __restrict__ maxx,
                          const float* __restrict__ sc, const float* __restrict__ sh,
                          short* __restrict__ feats) {
    int i = blockIdx.x * 256 + threadIdx.x;
    if (i >= B_ * P_ * 8) return;
    int c0 = (i & 7) * 8;
    size_t base = (size_t)(i >> 3) * 64 + c0;
    f32x4 v0 = *(const f32x4*)&maxx[base];
    f32x4 v1 = *(const f32x4*)&maxx[base + 4];
    ushort4 o0, o1;
    o0.x = f2bf(fmaxf(fmaf(v0[0], sc[c0+0], sh[c0+0]), 0.f));
    o0.y = f2bf(fmaxf(fmaf(v0[1], sc[c0+1], sh[c0+1]), 0.f));
    o0.z = f2bf(fmaxf(fmaf(v0[2], sc[c0+2], sh[c0+2]), 0.f));
    o0.w = f2bf(fmaxf(fmaf(v0[3], sc[c0+3], sh[c0+3]), 0.f));
    o1.x = f2bf(fmaxf(fmaf(v1[0], sc[c0+4], sh[c0+4]), 0.f));
    o1.y = f2bf(fmaxf(fmaf(v1[1], sc[c0+5], sh[c0+5]), 0.f));
    o1.z = f2bf(fmaxf(fmaf(v1[2], sc[c0+6], sh[c0+6]), 0.f));
    o1.w = f2bf(fmaxf(fmaf(v1[3], sc[c0+7], sh[c0+7]), 0.f));
    *(ushort4*)&feats[base] = o0;
    *(ushort4*)&feats[base + 4] = o1;
}

// ---------------- coords dtype probe ----------------
__global__ void k_probe_coords(const int* __restrict__ c32, int* __restrict__ flag) {
    int nz = 0;
    for (int i = 0; i < 512; ++i) nz |= c32[2*i + 1];
    *flag = (nz == 0) ? 1 : 0;
}

// ---- weight transform: f32 [Cout][Cin][3][3] -> bf16 frag order, bank-swizzled
__global__ void k_wt2(const float* __restrict__ src, short* __restrict__ dst,
                      int Cin, int MT, int NCB, int total) {
    int i = blockIdx.x * 256 + threadIdx.x;
    if (i >= total) return;
    int e = i & 7;  int t = i >> 3;
    int chunk = t & 63; t >>= 6;
    int n16 = chunk >> 2;
    int g = (chunk & 3) ^ ((n16 >> 1) & 3);
    int mt = t % MT;  t /= MT;
    int tap = t % 9;  t /= 9;
    int cb = t % NCB; int cg = t / NCB;
    int co = (cg * MT + mt) * 16 + n16;
    int ci = cb * 32 + g * 8 + e;
    dst[i] = (short)f2bf(src[((size_t)co * Cin + ci) * 9 + tap]);
}

__global__ void k_wt2_heads(const float* __restrict__ box, const float* __restrict__ cls,
                            const float* __restrict__ dir,
                            const float* __restrict__ boxb, const float* __restrict__ clsb,
                            const float* __restrict__ dirb,
                            short* __restrict__ dst, float* __restrict__ bias) {
    int i = blockIdx.x * 256 + threadIdx.x;      // 8cb*9*2*64chunks*8 = 73728
    if (i >= 73728) return;
    int e = i & 7;  int t = i >> 3;
    int chunk = t & 63; t >>= 6;
    int n16 = chunk >> 2;
    int g = (chunk & 3) ^ ((n16 >> 1) & 3);
    int mt = t & 1;   t >>= 1;
    int tap = t % 9;  int cb = t / 9;
    int oc = mt * 16 + n16;
    int ci = cb * 32 + g * 8 + e;
    float v = 0.f;
    if (oc < 21)      v = box[((size_t)oc * 256 + ci) * 9 + tap];
    else if (oc < 24) v = cls[((size_t)(oc - 21) * 256 + ci) * 9 + tap];
    else if (oc < 26) v = dir[((size_t)(oc - 24) * 256 + ci) * 9 + tap];
    dst[i] = (short)f2bf(v);
    if (i < 32) {
        float bv = 0.f;
        if (i < 21) bv = boxb[i];
        else if (i < 24) bv = clsb[i - 21];
        else if (i < 26) bv = dirb[i - 24];
        bias[i] = bv;
    }
}

// ---------------- scatter feats (or zeros) into padded half pseudo-image ----
template<bool CLEAR>
__global__ void k_scatter(const short* __restrict__ feats,
                          const int* __restrict__ coords32,
                          const int* __restrict__ flag64,
                          short* __restrict__ pseudo,
                          int b, int ylo, int yhi, int rowOff) {
    const int p = blockIdx.x * 4 + (threadIdx.x >> 6);
    const int c = threadIdx.x & 63;
    const int bp = b * P_ + p;
    long long y, x;
    if (*flag64) {
        const long long* c64 = (const long long*)coords32;
        y = c64[(size_t)bp*4 + 1];
        x = c64[(size_t)bp*4 + 2];
    } else {
        y = coords32[(size_t)bp*4 + 1];
        x = coords32[(size_t)bp*4 + 2];
    }
    if (y >= ylo && y < yhi && x >= 0 && x < W1_)
        pseudo[(((size_t)(y - 1 - rowOff + 1)) * PSH_W + (x + 1)) * 64 + c]
            = CLEAR ? (short)0 : feats[(size_t)bp * 64 + c];
}

// ---------------- bn + relu in place over padded interior ----------------
template<int C>
__global__ void k_bnrelu_pad(short* __restrict__ buf,
                             const float* __restrict__ sc, const float* __restrict__ sh,
                             int Hd, int Wd, int Hp, int Wp) {
    constexpr int OCT = C / 8;
    constexpr int LO = (C == 64) ? 3 : (C == 128) ? 4 : 5;
    size_t i = (size_t)blockIdx.x * 256 + threadIdx.x;
    size_t total = (size_t)B_ * Hd * Wd * OCT;
    if (i >= total) return;
    int oct = (int)(i & (OCT - 1));
    size_t t = i >> LO;
    int x = (int)(t % Wd); t /= Wd;
    int y = (int)(t % Hd);
    int b = (int)(t / Hd);
    size_t idx = (((size_t)b * Hp + y + 1) * Wp + x + 1) * C + oct * 8;
    uint4 v = *(uint4*)&buf[idx];
    unsigned short* u = (unsigned short*)&v;
#pragma unroll
    for (int j = 0; j < 8; ++j)
        u[j] = f2bf(fmaxf(fmaf(bf2f(u[j]), sc[oct*8 + j], sh[oct*8 + j]), 0.f));
    *(uint4*)&buf[idx] = v;
}

// ---------------- MFMA tap-GEMM conv3x3, R=4, 3-tap A-phases ----------------
// LDS cut to 37.9 KB (sA holds 3 taps at a time; dy==phase) -> 4 blocks/CU.
// Bank-conflict-free offsets unchanged (verified 0 conflicts in r8).
template<int CIN, int MT, bool POOL, bool STATS, bool HEADS>
__global__ __launch_bounds__(256) void k_mconv5(
    const short* __restrict__ in, const short* __restrict__ wt2,
    const float* __restrict__ bias,
    short* __restrict__ out, float* __restrict__ outf,
    float* __restrict__ sbuf,
    int Hp, int Wp, int rowOff, int yoff,
    int Win, int Hin, int HpO, int WpO, int CoutT, int cgCount) {

    constexpr int NCB = CIN / 32;
    constexpr int ATAPS = HEADS ? 9 : 3;
    constexpr int ACH = ATAPS * MT * 64;         // A 16B chunks per stage
    constexpr int BCH = 6 * 66 * 4;              // B 16B chunks per cb slice
    __shared__ short sA[ACH * 8];
    __shared__ short sB[HEADS ? 8 : BCH * 8];

    const int tid = threadIdx.x;
    const int lane = tid & 63, w = tid >> 6;
    const int n16 = lane & 15, g = lane >> 4;
    const int b  = blockIdx.z / cgCount;
    const int cg = blockIdx.z % cgCount;
    const int co0 = cg * (MT * 16);
    const int byp = blockIdx.y + yoff;
    const int cy0 = 4 * byp;
    const int x0 = blockIdx.x * 64;
    const int r0p = cy0 - 1 - rowOff;
    const int colbase = w * 16 + n16;
    const int xg = x0 + colbase;

    // conflict-free chunk offsets
    const int aoff = n16 * 4 + (g ^ ((n16 >> 1) & 3));
    int boff[3];
#pragma unroll
    for (int dx = 0; dx < 3; ++dx) {
        int cdx = colbase + dx;
        boff[dx] = cdx * 4 + (g ^ ((cdx >> 1) & 3));
    }

    f32x4 acc[4][MT];
#pragma unroll
    for (int r = 0; r < 4; ++r)
#pragma unroll
        for (int mt = 0; mt < MT; ++mt)
            acc[r][mt] = *(const f32x4*)&bias[co0 + mt * 16 + g * 4];

    const short* awBase = wt2 + (size_t)cg * NCB * 9 * (MT * 64) * 8;
    const short* bwBase = in + (((size_t)b * Hp + r0p) * Wp + x0) * CIN;
    size_t hBase = 0;
    if (HEADS)
        hBase = (((size_t)b * Hp + r0p) * Wp + x0 + colbase) * CIN + g * 8;

    for (int cb = 0; cb < NCB; ++cb) {
        if (HEADS) {
            // stage all 9 taps of A once; B read direct from padded global
            const short* aw = awBase + (size_t)(cb * 9) * (MT * 64) * 8;
            for (int cc0 = 0; cc0 < ACH; cc0 += 256) {
                int ch = cc0 + tid;
                if (ch < ACH)
                    gload16(aw + (size_t)ch * 8, &sA[(cc0 + w * 64) * 8]);
            }
            __syncthreads();
#pragma unroll
            for (int tap = 0; tap < 9; ++tap) {
                const int dy = tap / 3, dx = tap % 3;
                s16x8 a[MT], bf[4];
#pragma unroll
                for (int mt = 0; mt < MT; ++mt)
                    a[mt] = *(const s16x8*)&sA[((tap * MT + mt) * 64 + aoff) * 8];
#pragma unroll
                for (int r = 0; r < 4; ++r)
                    bf[r] = *(const s16x8*)&in[hBase + (size_t)((r + dy) * Wp + dx) * CIN + cb * 32];
#pragma unroll
                for (int r = 0; r < 4; ++r)
#pragma unroll
                    for (int mt = 0; mt < MT; ++mt)
                        acc[r][mt] = __builtin_amdgcn_mfma_f32_16x16x32_bf16(
                            a[mt], bf[r], acc[r][mt], 0, 0, 0);
            }
            __syncthreads();
        } else {
#pragma unroll
            for (int ph = 0; ph < 3; ++ph) {
                // stage A taps ph*3..ph*3+2 (contiguous in wt2 layout)
                const short* aw = awBase + (size_t)(cb * 9 + ph * 3) * (MT * 64) * 8;
                for (int cc0 = 0; cc0 < ACH; cc0 += 256) {
                    int ch = cc0 + tid;
                    if (ch < ACH)
                        gload16(aw + (size_t)ch * 8, &sA[(cc0 + w * 64) * 8]);
                }
                if (ph == 0) {
                    const short* bw = bwBase + cb * 32;
                    for (int cc0 = 0; cc0 < BCH; cc0 += 256) {
                        int ch = cc0 + tid;
                        if (ch < BCH) {
                            int oslot = ch & 3;
                            int col = (ch >> 2) % 66;
                            int row = ch / 264;
                            int oct = oslot ^ ((col >> 1) & 3);
                            gload16(bw + ((size_t)row * Wp + col) * CIN + oct * 8,
                                    &sB[(cc0 + w * 64) * 8]);
                        }
                    }
                }
                __syncthreads();
                // compute 3 taps; dy == ph, dx == tloc
#pragma unroll
                for (int tloc = 0; tloc < 3; ++tloc) {
                    s16x8 a[MT], bf[4];
#pragma unroll
                    for (int mt = 0; mt < MT; ++mt)
                        a[mt] = *(const s16x8*)&sA[((tloc * MT + mt) * 64 + aoff) * 8];
#pragma unroll
                    for (int r = 0; r < 4; ++r)
                        bf[r] = *(const s16x8*)&sB[((r + ph) * 264 + boff[tloc]) * 8];
#pragma unroll
                    for (int r = 0; r < 4; ++r)
#pragma unroll
                        for (int mt = 0; mt < MT; ++mt)
                            acc[r][mt] = __builtin_amdgcn_mfma_f32_16x16x32_bf16(
                                a[mt], bf[r], acc[r][mt], 0, 0, 0);
                }
                __syncthreads();
            }
        }
    }

    if (STATS) {
        const bool colok = xg < Win;
        float* mybuf = sbuf + (size_t)((blockIdx.x + blockIdx.y) & 63) * (2 * CoutT);
#pragma unroll
        for (int mt = 0; mt < MT; ++mt) {
#pragma unroll
            for (int reg = 0; reg < 4; ++reg) {
                float sv = 0.f, qv = 0.f;
                if (colok) {
#pragma unroll
                    for (int r = 0; r < 4; ++r) {
                        if (cy0 + r < Hin) {
                            float v = acc[r][mt][reg];
                            sv += v; qv += v * v;
                        }
                    }
                }
#pragma unroll
                for (int o = 1; o < 16; o <<= 1) {
                    sv += __shfl_xor(sv, o);
                    qv += __shfl_xor(qv, o);
                }
                if (n16 == 0) {
                    int c = co0 + mt * 16 + g * 4 + reg;
                    atomicAdd(&mybuf[c], sv);
                    atomicAdd(&mybuf[CoutT + c], qv);
                }
            }
        }
    }

    if (HEADS) {
        if (xg < Win) {
#pragma unroll
            for (int r = 0; r < 4; ++r) {
                if (cy0 + r >= Hin) continue;
#pragma unroll
                for (int mt = 0; mt < MT; ++mt)
#pragma unroll
                    for (int reg = 0; reg < 4; ++reg) {
                        int oc = co0 + mt * 16 + g * 4 + reg;
                        float v = acc[r][mt][reg];
                        size_t px = (size_t)(cy0 + r) * W3_ + xg;
                        if (oc < 21)
                            outf[((size_t)(b * 21 + oc)) * HW3 + px] = v;
                        else if (oc < 24)
                            outf[(size_t)4 * 21 * HW3 + ((size_t)(b * 3 + oc - 21)) * HW3 + px] = v;
                        else if (oc < 26)
                            outf[(size_t)4 * 24 * HW3 + ((size_t)(b * 2 + oc - 24)) * HW3 + px] = v;
                    }
            }
        }
    } else if (POOL) {
        const bool colok = ((n16 & 1) == 0) && (xg + 1 < Win);
#pragma unroll
        for (int k = 0; k < 2; ++k) {
            const int py = 2 * byp + k;
            const bool rowok = (2 * py + 1 < Hin);
#pragma unroll
            for (int mt = 0; mt < MT; ++mt) {
                float pv[4];
#pragma unroll
                for (int reg = 0; reg < 4; ++reg) {
                    float v = fmaxf(acc[2*k][mt][reg], acc[2*k+1][mt][reg]);
                    v = fmaxf(v, __shfl_xor(v, 1));
                    pv[reg] = v;
                }
                if (colok && rowok) {
                    size_t o = (((size_t)b * HpO + py + 1) * WpO + (xg >> 1) + 1) * CoutT
                               + co0 + mt * 16 + g * 4;
                    ushort4 pk = { f2bf(pv[0]), f2bf(pv[1]), f2bf(pv[2]), f2bf(pv[3]) };
                    *(ushort4*)&out[o] = pk;
                }
            }
        }
    } else {
        if (xg < Win) {
#pragma unroll
            for (int r = 0; r < 4; ++r) {
                if (cy0 + r >= Hin) continue;
#pragma unroll
                for (int mt = 0; mt < MT; ++mt) {
                    size_t o = (((size_t)b * HpO + cy0 + r + 1) * WpO + xg + 1) * CoutT
                               + co0 + mt * 16 + g * 4;
                    ushort4 pk = { f2bf(acc[r][mt][0]), f2bf(acc[r][mt][1]),
                                   f2bf(acc[r][mt][2]), f2bf(acc[r][mt][3]) };
                    *(ushort4*)&out[o] = pk;
                }
            }
        }
    }
}

extern "C" void kernel_launch(void* const* d_in, const int* in_sizes, int n_in,
                              void* d_out, int out_size, void* d_ws, size_t ws_size,
                              hipStream_t stream) {
    const float* pillars = (const float*)d_in[0];
    const int*   coords  = (const int*)d_in[1];
    const float* lin_w = (const float*)d_in[2];
    const float* lin_b = (const float*)d_in[3];
    const float* bn0_g = (const float*)d_in[4];
    const float* bn0_b = (const float*)d_in[5];
    const float* c1_w  = (const float*)d_in[6];
    const float* c1_b  = (const float*)d_in[7];
    const float* bn1_g = (const float*)d_in[8];
    const float* bn1_b = (const float*)d_in[9];
    const float* c2_w  = (const float*)d_in[10];
    const float* c2_b  = (const float*)d_in[11];
    const float* bn2_g = (const float*)d_in[12];
    const float* bn2_b = (const float*)d_in[13];
    const float* h1_w  = (const float*)d_in[14];
    const float* h1_b  = (const float*)d_in[15];
    const float* hbn_g = (const float*)d_in[16];
    const float* hbn_b = (const float*)d_in[17];
    const float* box_w = (const float*)d_in[18];
    const float* box_b = (const float*)d_in[19];
    const float* cls_w = (const float*)d_in[20];
    const float* cls_b = (const float*)d_in[21];
    const float* dir_w = (const float*)d_in[22];
    const float* dir_b = (const float*)d_in[23];

    // ---- workspace layout ----
    const size_t szPseudo = (size_t)PSH_H * PSH_W * 64 * 2;
    const size_t szP1  = (size_t)B_ * P1_H * P1_W * 64 * 2;
    const size_t szP2  = (size_t)B_ * P2_H * P2_W * 128 * 2;
    const size_t szH1p = (size_t)B_ * P2_H * P2_W * 256 * 2;
    const size_t szR1 = szH1p;
    const size_t szR2 = szP2;
    const size_t offR1 = 0;
    const size_t offR2 = szR1;
    const size_t offFeats = offR2 + szR2;
    const size_t szFeats = (size_t)B_ * P_ * 64 * 2;
    const size_t offC1W = offFeats + szFeats;
    const size_t offC2W = offC1W + 73728;
    const size_t offH1W = offC2W + 147456;
    const size_t offHDW = offH1W + 589824;
    const size_t offArena = offHDW + 147456;
    const size_t wsNeeded = offArena + 300000;
    char* ws = (char*)d_ws;

    if (ws_size < wsNeeded) {
        float mb = (float)(double)(ws_size >> 20);
        k_diag<<<(out_size + 255) / 256, 256, 0, stream>>>((float*)d_out, out_size, mb);
        return;
    }

    float* F = (float*)(ws + offArena);
    float* sbuf0 = F;
    float* L1buf = F + 8192;
    float* L2buf = F + 16384;
    float* L3buf = F + 32768;
    float* sc0 = F + 65536; float* sh0 = F + 65600;
    float* sc1 = F + 65664; float* sh1 = F + 65728;
    float* sc2 = F + 65792; float* sh2 = F + 65920;
    float* sc3 = F + 66048; float* sh3 = F + 66304;
    float* hdbias = F + 66560;
    int* flag64 = (int*)(F + 66596);

    short* pooled1 = (short*)(ws + offR1);
    short* h1p     = (short*)(ws + offR1);
    float* maxx    = (float*)(ws + offR2);
    short* pseudo  = (short*)(ws + offR2);
    short* pooled2 = (short*)(ws + offR2);
    short* feats   = (short*)(ws + offFeats);
    short* c1wt = (short*)(ws + offC1W);
    short* c2wt = (short*)(ws + offC2W);
    short* h1wt = (short*)(ws + offH1W);
    short* hdwt = (short*)(ws + offHDW);

    hipMemsetAsync(ws + offArena, 0, 262144, stream);
    hipMemsetAsync(ws + offR1, 0, szP1, stream);
    k_probe_coords<<<1, 1, 0, stream>>>(coords, flag64);

    k_wt2<<<(64*64*9 + 255)/256, 256, 0, stream>>>(c1_w, c1wt, 64, 4, 2, 64*64*9);
    k_wt2<<<(128*64*9 + 255)/256, 256, 0, stream>>>(c2_w, c2wt, 64, 4, 2, 128*64*9);
    k_wt2<<<(256*128*9 + 255)/256, 256, 0, stream>>>(h1_w, h1wt, 128, 4, 4, 256*128*9);
    k_wt2_heads<<<(73728 + 255)/256, 256, 0, stream>>>(box_w, cls_w, dir_w,
                                                       box_b, cls_b, dir_b,
                                                       hdwt, hdbias);

    // pillar stage
    k_linmax<<<B_ * P_ * N_ / 256, 256, 0, stream>>>(pillars, lin_w, lin_b, maxx, sbuf0);
    k_finalize2<<<1, 64, 0, stream>>>(sbuf0, bn0_g, bn0_b, sc0, sh0, 64,
                                      1.0f / (float)(B_ * P_ * N_));
    k_featsbn<<<(B_ * P_ * 8 + 255)/256, 256, 0, stream>>>(maxx, sc0, sh0, feats);

    // conv1 (64->64 @666^2, raw pool -> pooled1), per (batch, half)
    hipMemsetAsync(pseudo, 0, szPseudo, stream);
    for (int b = 0; b < B_; ++b) {
        for (int h = 0; h < 2; ++h) {
            const int ylo = h ? 335 : 0;
            const int yhi = h ? 666 : 337;
            const int rowOff = h ? 335 : -1;
            const int yoff = h ? 84 : 0;
            const int ny = h ? 83 : 84;
            k_scatter<false><<<P_ / 4, 256, 0, stream>>>(feats, coords, flag64, pseudo,
                                                         b, ylo, yhi, rowOff);
            dim3 gr(11, ny, 1);
            k_mconv5<64, 4, true, true, false><<<gr, 256, 0, stream>>>(
                pseudo, c1wt, c1_b,
                pooled1 + (size_t)b * P1_H * P1_W * 64, nullptr, L1buf,
                PSH_H, PSH_W, rowOff, yoff, W1_, H1_, P1_H, P1_W, 64, 1);
            k_scatter<true><<<P_ / 4, 256, 0, stream>>>(feats, coords, flag64, pseudo,
                                                        b, ylo, yhi, rowOff);
        }
    }
    k_finalize2<<<1, 64, 0, stream>>>(L1buf, bn1_g, bn1_b, sc1, sh1, 64,
                                      1.0f / ((float)B_ * HW1));
    {
        size_t total = (size_t)B_ * H2_ * W2_ * 8;
        k_bnrelu_pad<64><<<(unsigned)((total + 255) / 256), 256, 0, stream>>>(
            pooled1, sc1, sh1, H2_, W2_, P1_H, P1_W);
    }

    // conv2 (64->128 @333^2, raw pool -> pooled2)
    hipMemsetAsync(ws + offR2, 0, szP2, stream);
    {
        dim3 gr(6, 84, 2 * B_);
        k_mconv5<64, 4, true, true, false><<<gr, 256, 0, stream>>>(
            pooled1, c2wt, c2_b, pooled2, nullptr, L2buf,
            P1_H, P1_W, -1, 0, W2_, H2_, P2_H, P2_W, 128, 2);
    }
    k_finalize2<<<1, 128, 0, stream>>>(L2buf, bn2_g, bn2_b, sc2, sh2, 128,
                                       1.0f / ((float)B_ * HW2));
    {
        size_t total = (size_t)B_ * H3_ * W3_ * 16;
        k_bnrelu_pad<128><<<(unsigned)((total + 255) / 256), 256, 0, stream>>>(
            pooled2, sc2, sh2, H3_, W3_, P2_H, P2_W);
    }

    // h1 (128->256 @166^2, 4 out rows/block) -> h1p raw
    hipMemsetAsync(ws + offR1, 0, szH1p, stream);
    {
        dim3 gr(3, 42, 4 * B_);
        k_mconv5<128, 4, false, true, false><<<gr, 256, 0, stream>>>(
            pooled2, h1wt, h1_b, h1p, nullptr, L3buf,
            P2_H, P2_W, -1, 0, W3_, H3_, P2_H, P2_W, 256, 4);
    }
    k_finalize2<<<1, 256, 0, stream>>>(L3buf, hbn_g, hbn_b, sc3, sh3, 256,
                                       1.0f / ((float)B_ * HW3));
    {
        size_t total = (size_t)B_ * H3_ * W3_ * 32;
        k_bnrelu_pad<256><<<(unsigned)((total + 255) / 256), 256, 0, stream>>>(
            h1p, sc3, sh3, H3_, W3_, P2_H, P2_W);
    }

    // heads: fused 26-channel conv, f32 out
    {
        dim3 gr(3, 42, B_);
        k_mconv5<256, 2, false, false, true><<<gr, 256, 0, stream>>>(
            h1p, hdwt, hdbias, nullptr, (float*)d_out, nullptr,
            P2_H, P2_W, -1, 0, W3_, H3_, P2_H, P2_W, 32, 1);
    }
}

// Round 12
// 616.913 us; speedup vs baseline: 1.4766x; 1.2761x over previous
//
#include <hip/hip_runtime.h>
#include <hip/hip_bf16.h>

#define B_ 4
#define P_ 12000
#define N_ 32
#define H1_ 666
#define W1_ 666
#define HW1 (H1_*W1_)
#define H2_ 333
#define W2_ 333
#define HW2 (H2_*W2_)
#define H3_ 166
#define W3_ 166
#define HW3 (H3_*W3_)
#define EPS_ 1e-5f

// padded channels-last buffer dims
#define P1_H 340
#define P1_W 388
#define P2_H 172
#define P2_W 196
// idxmap padded dims
#define IDX_H 672
#define IDX_W 708

typedef short s16x8 __attribute__((ext_vector_type(8)));
typedef float f32x4 __attribute__((ext_vector_type(4)));

__device__ __forceinline__ unsigned short f2bf(float f) {
    unsigned int x = __float_as_uint(f);
    return (unsigned short)((x + 0x7fffu + ((x >> 16) & 1u)) >> 16);
}
__device__ __forceinline__ float bf2f(unsigned short u) {
    return __uint_as_float(((unsigned int)u) << 16);
}

__device__ __forceinline__ void gload16(const void* g, void* l) {
    __builtin_amdgcn_global_load_lds(
        (const __attribute__((address_space(1))) void*)g,
        (__attribute__((address_space(3))) void*)l, 16, 0, 0);
}

// ---------------- diagnostic fill ----------------
__global__ void k_diag(float* __restrict__ out, int n, float val) {
    int i = blockIdx.x * 256 + threadIdx.x;
    if (i < n) out[i] = val;
}

// ---------------- fused pillar linear + BN0 stats + max over N ----------------
__global__ __launch_bounds__(256) void k_linmax(
    const float* __restrict__ pillars,
    const float* __restrict__ lin_w, const float* __restrict__ lin_b,
    float* __restrict__ maxx, float* __restrict__ sbuf) {
    __shared__ float xs[64 * 268];
    __shared__ float wsm[64 * 10];
    const int tid = threadIdx.x;
    if (tid < 64) {
#pragma unroll
        for (int j = 0; j < 9; ++j) wsm[tid * 10 + j] = lin_w[tid * 9 + j];
        wsm[tid * 10 + 9] = lin_b[tid];
    }
    __syncthreads();
    const float* p = pillars + (size_t)(blockIdx.x * 256 + tid) * 9;
    float f0=p[0], f1=p[1], f2=p[2], f3=p[3], f4=p[4],
          f5=p[5], f6=p[6], f7=p[7], f8=p[8];
#pragma unroll
    for (int c = 0; c < 64; ++c) {
        const float* wc = &wsm[c * 10];
        float x = wc[9] + wc[0]*f0 + wc[1]*f1 + wc[2]*f2 + wc[3]*f3 + wc[4]*f4
                        + wc[5]*f5 + wc[6]*f6 + wc[7]*f7 + wc[8]*f8;
        xs[c * 268 + tid] = x;
    }
    __syncthreads();
    const int c = tid & 63;
    const int w = tid >> 6;
    float s = 0.f, q = 0.f;
#pragma unroll
    for (int pi = 0; pi < 2; ++pi) {
        const int pp = w + pi * 4;
        float mx = -3e38f;
#pragma unroll
        for (int j = 0; j < 32; j += 4) {
            f32x4 v = *(const f32x4*)&xs[c * 268 + pp * 32 + j];
            s += v[0] + v[1] + v[2] + v[3];
            q += v[0]*v[0] + v[1]*v[1] + v[2]*v[2] + v[3]*v[3];
            mx = fmaxf(mx, fmaxf(fmaxf(v[0], v[1]), fmaxf(v[2], v[3])));
        }
        maxx[(size_t)(blockIdx.x * 8 + pp) * 64 + c] = mx;
    }
    float* mybuf = sbuf + (size_t)(blockIdx.x & 63) * 128;
    atomicAdd(&mybuf[c], s);
    atomicAdd(&mybuf[64 + c], q);
}

// ---------------- BN finalize from 64 contention buffers ----------------
__global__ void k_finalize2(const float* __restrict__ bufs,
                            const float* __restrict__ g, const float* __restrict__ b,
                            float* __restrict__ scale, float* __restrict__ shift,
                            int C, float invN) {
    int c = blockIdx.x * 256 + threadIdx.x;
    if (c >= C) return;
    float s = 0.f, q = 0.f;
    for (int k = 0; k < 64; ++k) {
        s += bufs[(size_t)k * 2 * C + c];
        q += bufs[(size_t)k * 2 * C + C + c];
    }
    float m = s * invN;
    float v = q * invN - m * m;
    float sc = g[c] * rsqrtf(v + EPS_);
    scale[c] = sc;
    shift[c] = b[c] - m * sc;
}

// ---------------- feats (slot bp+1) = bf16(relu(bn(maxx))) ----------------
__global__ void k_featsbn(const float* __restrict__ maxx,
                          const float* __restrict__ sc, const float* __restrict__ sh,
                          short* __restrict__ feats) {
    int i = blockIdx.x * 256 + threadIdx.x;
    if (i >= B_ * P_ * 8) return;
    int c0 = (i & 7) * 8;
    size_t src = (size_t)(i >> 3) * 64 + c0;
    size_t dst = ((size_t)(i >> 3) + 1) * 64 + c0;   // slot 0 = zeros
    f32x4 v0 = *(const f32x4*)&maxx[src];
    f32x4 v1 = *(const f32x4*)&maxx[src + 4];
    ushort4 o0, o1;
    o0.x = f2bf(fmaxf(fmaf(v0[0], sc[c0+0], sh[c0+0]), 0.f));
    o0.y = f2bf(fmaxf(fmaf(v0[1], sc[c0+1], sh[c0+1]), 0.f));
    o0.z = f2bf(fmaxf(fmaf(v0[2], sc[c0+2], sh[c0+2]), 0.f));
    o0.w = f2bf(fmaxf(fmaf(v0[3], sc[c0+3], sh[c0+3]), 0.f));
    o1.x = f2bf(fmaxf(fmaf(v1[0], sc[c0+4], sh[c0+4]), 0.f));
    o1.y = f2bf(fmaxf(fmaf(v1[1], sc[c0+5], sh[c0+5]), 0.f));
    o1.z = f2bf(fmaxf(fmaf(v1[2], sc[c0+6], sh[c0+6]), 0.f));
    o1.w = f2bf(fmaxf(fmaf(v1[3], sc[c0+7], sh[c0+7]), 0.f));
    *(ushort4*)&feats[dst] = o0;
    *(ushort4*)&feats[dst + 4] = o1;
}

// ---------------- coords dtype probe ----------------
__global__ void k_probe_coords(const int* __restrict__ c32, int* __restrict__ flag) {
    int nz = 0;
    for (int i = 0; i < 512; ++i) nz |= c32[2*i + 1];
    *flag = (nz == 0) ? 1 : 0;
}

// ---------------- idx scatter: idxmap[b][y+1][x+1] = bp + 1 ----------------
__global__ void k_idxscatter(const int* __restrict__ coords32,
                             const int* __restrict__ flag64,
                             int* __restrict__ idxmap) {
    int bp = blockIdx.x * 256 + threadIdx.x;
    if (bp >= B_ * P_) return;
    long long y, x;
    if (*flag64) {
        const long long* c64 = (const long long*)coords32;
        y = c64[(size_t)bp*4 + 1];
        x = c64[(size_t)bp*4 + 2];
    } else {
        y = coords32[(size_t)bp*4 + 1];
        x = coords32[(size_t)bp*4 + 2];
    }
    int b = bp / P_;
    if (y >= 0 && y < H1_ && x >= 0 && x < W1_)
        idxmap[((size_t)b * IDX_H + (y + 1)) * IDX_W + (x + 1)] = bp + 1;
}

// ---- weight transform: f32 [Cout][Cin][3][3] -> bf16 frag order, bank-swizzled
__global__ void k_wt2(const float* __restrict__ src, short* __restrict__ dst,
                      int Cin, int MT, int NCB, int total) {
    int i = blockIdx.x * 256 + threadIdx.x;
    if (i >= total) return;
    int e = i & 7;  int t = i >> 3;
    int chunk = t & 63; t >>= 6;
    int n16 = chunk >> 2;
    int g = (chunk & 3) ^ ((n16 >> 1) & 3);
    int mt = t % MT;  t /= MT;
    int tap = t % 9;  t /= 9;
    int cb = t % NCB; int cg = t / NCB;
    int co = (cg * MT + mt) * 16 + n16;
    int ci = cb * 32 + g * 8 + e;
    dst[i] = (short)f2bf(src[((size_t)co * Cin + ci) * 9 + tap]);
}

__global__ void k_wt2_heads(const float* __restrict__ box, const float* __restrict__ cls,
                            const float* __restrict__ dir,
                            const float* __restrict__ boxb, const float* __restrict__ clsb,
                            const float* __restrict__ dirb,
                            short* __restrict__ dst, float* __restrict__ bias) {
    int i = blockIdx.x * 256 + threadIdx.x;      // 8cb*9*2*64chunks*8 = 73728
    if (i >= 73728) return;
    int e = i & 7;  int t = i >> 3;
    int chunk = t & 63; t >>= 6;
    int n16 = chunk >> 2;
    int g = (chunk & 3) ^ ((n16 >> 1) & 3);
    int mt = t & 1;   t >>= 1;
    int tap = t % 9;  int cb = t / 9;
    int oc = mt * 16 + n16;
    int ci = cb * 32 + g * 8 + e;
    float v = 0.f;
    if (oc < 21)      v = box[((size_t)oc * 256 + ci) * 9 + tap];
    else if (oc < 24) v = cls[((size_t)(oc - 21) * 256 + ci) * 9 + tap];
    else if (oc < 26) v = dir[((size_t)(oc - 24) * 256 + ci) * 9 + tap];
    dst[i] = (short)f2bf(v);
    if (i < 32) {
        float bv = 0.f;
        if (i < 21) bv = boxb[i];
        else if (i < 24) bv = clsb[i - 21];
        else if (i < 26) bv = dirb[i - 24];
        bias[i] = bv;
    }
}

// ---------------- bn + relu in place over padded interior ----------------
template<int C>
__global__ void k_bnrelu_pad(short* __restrict__ buf,
                             const float* __restrict__ sc, const float* __restrict__ sh,
                             int Hd, int Wd, int Hp, int Wp) {
    constexpr int OCT = C / 8;
    constexpr int LO = (C == 64) ? 3 : (C == 128) ? 4 : 5;
    size_t i = (size_t)blockIdx.x * 256 + threadIdx.x;
    size_t total = (size_t)B_ * Hd * Wd * OCT;
    if (i >= total) return;
    int oct = (int)(i & (OCT - 1));
    size_t t = i >> LO;
    int x = (int)(t % Wd); t /= Wd;
    int y = (int)(t % Hd);
    int b = (int)(t / Hd);
    size_t idx = (((size_t)b * Hp + y + 1) * Wp + x + 1) * C + oct * 8;
    uint4 v = *(uint4*)&buf[idx];
    unsigned short* u = (unsigned short*)&v;
#pragma unroll
    for (int j = 0; j < 8; ++j)
        u[j] = f2bf(fmaxf(fmaf(bf2f(u[j]), sc[oct*8 + j], sh[oct*8 + j]), 0.f));
    *(uint4*)&buf[idx] = v;
}

// ---------------- MFMA tap-GEMM conv3x3, R=4 (r8 structure, 0 conflicts) ----
// IDX: B staged by gathering feats[idxmap[...]] (per-lane global src for
// global_load_lds); idx 0 -> feats slot 0 (zeros).
template<int CIN, int MT, bool POOL, bool STATS, bool HEADS, bool IDX>
__global__ __launch_bounds__(256) void k_mconv6(
    const short* __restrict__ in, const short* __restrict__ wt2,
    const float* __restrict__ bias,
    const int* __restrict__ idxmap, const short* __restrict__ feats,
    short* __restrict__ out, float* __restrict__ outf,
    float* __restrict__ sbuf,
    int Hp, int Wp, int rowOff, int yoff,
    int Win, int Hin, int HpO, int WpO, int CoutT, int cgCount) {

    constexpr int NCB = CIN / 32;
    constexpr int ACH = 9 * MT * 64;
    constexpr int BCH = 6 * 66 * 4;
    __shared__ short sA[ACH * 8];
    __shared__ short sB[BCH * 8];

    const int tid = threadIdx.x;
    const int lane = tid & 63, w = tid >> 6;
    const int n16 = lane & 15, g = lane >> 4;
    const int b  = blockIdx.z / cgCount;
    const int cg = blockIdx.z % cgCount;
    const int co0 = cg * (MT * 16);
    const int byp = blockIdx.y + yoff;
    const int cy0 = 4 * byp;
    const int x0 = blockIdx.x * 64;
    const int r0p = cy0 - 1 - rowOff;
    const int colbase = w * 16 + n16;
    const int xg = x0 + colbase;

    // conflict-free chunk offsets
    const int aoff = n16 * 4 + (g ^ ((n16 >> 1) & 3));
    int boff[3];
#pragma unroll
    for (int dx = 0; dx < 3; ++dx) {
        int cdx = colbase + dx;
        boff[dx] = cdx * 4 + (g ^ ((cdx >> 1) & 3));
    }

    f32x4 acc[4][MT];
#pragma unroll
    for (int r = 0; r < 4; ++r)
#pragma unroll
        for (int mt = 0; mt < MT; ++mt)
            acc[r][mt] = *(const f32x4*)&bias[co0 + mt * 16 + g * 4];

    const int* imBase = IDX ? (idxmap + ((size_t)b * Hp + r0p) * Wp + x0) : nullptr;
    const short* bwBase = IDX ? nullptr
                              : (in + (((size_t)b * Hp + r0p) * Wp + x0) * CIN);

    for (int cb = 0; cb < NCB; ++cb) {
        const short* aw = wt2 + (size_t)(cg * NCB + cb) * ACH * 8;
        for (int cc0 = 0; cc0 < ACH; cc0 += 256) {
            int ch = cc0 + tid;
            if (ch < ACH)
                gload16(aw + (size_t)ch * 8, &sA[(cc0 + w * 64) * 8]);
        }
        for (int cc0 = 0; cc0 < BCH; cc0 += 256) {
            int ch = cc0 + tid;
            if (ch < BCH) {
                int oslot = ch & 3;
                int col = (ch >> 2) % 66;
                int row = ch / 264;
                int oct = oslot ^ ((col >> 1) & 3);
                if (IDX) {
                    int idx = imBase[(size_t)row * Wp + col];
                    gload16(feats + ((size_t)idx << 6) + (oct << 3) + cb * 32,
                            &sB[(cc0 + w * 64) * 8]);
                } else {
                    gload16(bwBase + cb * 32 + ((size_t)row * Wp + col) * CIN + oct * 8,
                            &sB[(cc0 + w * 64) * 8]);
                }
            }
        }
        __syncthreads();
#pragma unroll
        for (int tap = 0; tap < 9; ++tap) {
            const int dy = tap / 3, dx = tap % 3;
            s16x8 a[MT], bf[4];
#pragma unroll
            for (int mt = 0; mt < MT; ++mt)
                a[mt] = *(const s16x8*)&sA[((tap * MT + mt) * 64 + aoff) * 8];
#pragma unroll
            for (int r = 0; r < 4; ++r)
                bf[r] = *(const s16x8*)&sB[((r + dy) * 264 + boff[dx]) * 8];
#pragma unroll
            for (int r = 0; r < 4; ++r)
#pragma unroll
                for (int mt = 0; mt < MT; ++mt)
                    acc[r][mt] = __builtin_amdgcn_mfma_f32_16x16x32_bf16(
                        a[mt], bf[r], acc[r][mt], 0, 0, 0);
        }
        __syncthreads();
    }

    if (STATS) {
        const bool colok = xg < Win;
        float* mybuf = sbuf + (size_t)((blockIdx.x + blockIdx.y) & 63) * (2 * CoutT);
#pragma unroll
        for (int mt = 0; mt < MT; ++mt) {
#pragma unroll
            for (int reg = 0; reg < 4; ++reg) {
                float sv = 0.f, qv = 0.f;
                if (colok) {
#pragma unroll
                    for (int r = 0; r < 4; ++r) {
                        if (cy0 + r < Hin) {
                            float v = acc[r][mt][reg];
                            sv += v; qv += v * v;
                        }
                    }
                }
#pragma unroll
                for (int o = 1; o < 16; o <<= 1) {
                    sv += __shfl_xor(sv, o);
                    qv += __shfl_xor(qv, o);
                }
                if (n16 == 0) {
                    int c = co0 + mt * 16 + g * 4 + reg;
                    atomicAdd(&mybuf[c], sv);
                    atomicAdd(&mybuf[CoutT + c], qv);
                }
            }
        }
    }

    if (HEADS) {
        if (xg < Win) {
#pragma unroll
            for (int r = 0; r < 4; ++r) {
                if (cy0 + r >= Hin) continue;
#pragma unroll
                for (int mt = 0; mt < MT; ++mt)
#pragma unroll
                    for (int reg = 0; reg < 4; ++reg) {
                        int oc = co0 + mt * 16 + g * 4 + reg;
                        float v = acc[r][mt][reg];
                        size_t px = (size_t)(cy0 + r) * W3_ + xg;
                        if (oc < 21)
                            outf[((size_t)(b * 21 + oc)) * HW3 + px] = v;
                        else if (oc < 24)
                            outf[(size_t)4 * 21 * HW3 + ((size_t)(b * 3 + oc - 21)) * HW3 + px] = v;
                        else if (oc < 26)
                            outf[(size_t)4 * 24 * HW3 + ((size_t)(b * 2 + oc - 24)) * HW3 + px] = v;
                    }
            }
        }
    } else if (POOL) {
        const bool colok = ((n16 & 1) == 0) && (xg + 1 < Win);
#pragma unroll
        for (int k = 0; k < 2; ++k) {
            const int py = 2 * byp + k;
            const bool rowok = (2 * py + 1 < Hin);
#pragma unroll
            for (int mt = 0; mt < MT; ++mt) {
                float pv[4];
#pragma unroll
                for (int reg = 0; reg < 4; ++reg) {
                    float v = fmaxf(acc[2*k][mt][reg], acc[2*k+1][mt][reg]);
                    v = fmaxf(v, __shfl_xor(v, 1));
                    pv[reg] = v;
                }
                if (colok && rowok) {
                    size_t o = (((size_t)b * HpO + py + 1) * WpO + (xg >> 1) + 1) * CoutT
                               + co0 + mt * 16 + g * 4;
                    ushort4 pk = { f2bf(pv[0]), f2bf(pv[1]), f2bf(pv[2]), f2bf(pv[3]) };
                    *(ushort4*)&out[o] = pk;
                }
            }
        }
    } else {
        if (xg < Win) {
#pragma unroll
            for (int r = 0; r < 4; ++r) {
                if (cy0 + r >= Hin) continue;
#pragma unroll
                for (int mt = 0; mt < MT; ++mt) {
                    size_t o = (((size_t)b * HpO + cy0 + r + 1) * WpO + xg + 1) * CoutT
                               + co0 + mt * 16 + g * 4;
                    ushort4 pk = { f2bf(acc[r][mt][0]), f2bf(acc[r][mt][1]),
                                   f2bf(acc[r][mt][2]), f2bf(acc[r][mt][3]) };
                    *(ushort4*)&out[o] = pk;
                }
            }
        }
    }
}

extern "C" void kernel_launch(void* const* d_in, const int* in_sizes, int n_in,
                              void* d_out, int out_size, void* d_ws, size_t ws_size,
                              hipStream_t stream) {
    const float* pillars = (const float*)d_in[0];
    const int*   coords  = (const int*)d_in[1];
    const float* lin_w = (const float*)d_in[2];
    const float* lin_b = (const float*)d_in[3];
    const float* bn0_g = (const float*)d_in[4];
    const float* bn0_b = (const float*)d_in[5];
    const float* c1_w  = (const float*)d_in[6];
    const float* c1_b  = (const float*)d_in[7];
    const float* bn1_g = (const float*)d_in[8];
    const float* bn1_b = (const float*)d_in[9];
    const float* c2_w  = (const float*)d_in[10];
    const float* c2_b  = (const float*)d_in[11];
    const float* bn2_g = (const float*)d_in[12];
    const float* bn2_b = (const float*)d_in[13];
    const float* h1_w  = (const float*)d_in[14];
    const float* h1_b  = (const float*)d_in[15];
    const float* hbn_g = (const float*)d_in[16];
    const float* hbn_b = (const float*)d_in[17];
    const float* box_w = (const float*)d_in[18];
    const float* box_b = (const float*)d_in[19];
    const float* cls_w = (const float*)d_in[20];
    const float* cls_b = (const float*)d_in[21];
    const float* dir_w = (const float*)d_in[22];
    const float* dir_b = (const float*)d_in[23];

    // ---- workspace layout ----
    const size_t szP1  = (size_t)B_ * P1_H * P1_W * 64 * 2;       // 67,543,040
    const size_t szP2  = (size_t)B_ * P2_H * P2_W * 128 * 2;      // 34,521,088
    const size_t szH1p = (size_t)B_ * P2_H * P2_W * 256 * 2;      // 69,042,176
    const size_t szR1 = szH1p;                                    // pooled1 | h1p
    const size_t szR2 = szP2;                                     // maxx+idxmap | pooled2
    const size_t szIdx = (size_t)B_ * IDX_H * IDX_W * 4;          //  7,612,416
    const size_t offR1 = 0;
    const size_t offR2 = szR1;
    const size_t offIdx = offR2 + 12582912;                       // after maxx (12.29MB)
    const size_t offFeats = offR2 + szR2;
    const size_t szFeats = (size_t)(B_ * P_ + 1) * 64 * 2;        // slot0 = zeros
    const size_t offC1W = offFeats + szFeats;
    const size_t offC2W = offC1W + 73728;
    const size_t offH1W = offC2W + 147456;
    const size_t offHDW = offH1W + 589824;
    const size_t offArena = offHDW + 147456;
    const size_t wsNeeded = offArena + 300000;
    char* ws = (char*)d_ws;

    if (ws_size < wsNeeded) {
        float mb = (float)(double)(ws_size >> 20);
        k_diag<<<(out_size + 255) / 256, 256, 0, stream>>>((float*)d_out, out_size, mb);
        return;
    }

    float* F = (float*)(ws + offArena);
    float* sbuf0 = F;
    float* L1buf = F + 8192;
    float* L2buf = F + 16384;
    float* L3buf = F + 32768;
    float* sc0 = F + 65536; float* sh0 = F + 65600;
    float* sc1 = F + 65664; float* sh1 = F + 65728;
    float* sc2 = F + 65792; float* sh2 = F + 65920;
    float* sc3 = F + 66048; float* sh3 = F + 66304;
    float* hdbias = F + 66560;
    int* flag64 = (int*)(F + 66596);

    short* pooled1 = (short*)(ws + offR1);
    short* h1p     = (short*)(ws + offR1);
    float* maxx    = (float*)(ws + offR2);
    short* pooled2 = (short*)(ws + offR2);
    int*   idxmap  = (int*)(ws + offIdx);
    short* feats   = (short*)(ws + offFeats);
    short* c1wt = (short*)(ws + offC1W);
    short* c2wt = (short*)(ws + offC2W);
    short* h1wt = (short*)(ws + offH1W);
    short* hdwt = (short*)(ws + offHDW);

    hipMemsetAsync(ws + offArena, 0, 262144, stream);
    hipMemsetAsync(ws + offIdx, 0, szIdx, stream);       // idx 0 = zero slot
    hipMemsetAsync(ws + offFeats, 0, 128, stream);       // feats slot 0 = zeros
    hipMemsetAsync(ws + offR1, 0, szP1, stream);         // pooled1 + padding
    k_probe_coords<<<1, 1, 0, stream>>>(coords, flag64);
    k_idxscatter<<<(B_ * P_ + 255)/256, 256, 0, stream>>>(coords, flag64, idxmap);

    k_wt2<<<(64*64*9 + 255)/256, 256, 0, stream>>>(c1_w, c1wt, 64, 4, 2, 64*64*9);
    k_wt2<<<(128*64*9 + 255)/256, 256, 0, stream>>>(c2_w, c2wt, 64, 4, 2, 128*64*9);
    k_wt2<<<(256*128*9 + 255)/256, 256, 0, stream>>>(h1_w, h1wt, 128, 4, 4, 256*128*9);
    k_wt2_heads<<<(73728 + 255)/256, 256, 0, stream>>>(box_w, cls_w, dir_w,
                                                       box_b, cls_b, dir_b,
                                                       hdwt, hdbias);

    // pillar stage
    k_linmax<<<B_ * P_ * N_ / 256, 256, 0, stream>>>(pillars, lin_w, lin_b, maxx, sbuf0);
    k_finalize2<<<1, 64, 0, stream>>>(sbuf0, bn0_g, bn0_b, sc0, sh0, 64,
                                      1.0f / (float)(B_ * P_ * N_));
    k_featsbn<<<(B_ * P_ * 8 + 255)/256, 256, 0, stream>>>(maxx, sc0, sh0, feats);

    // conv1 (64->64 @666^2, idx-gathered input, raw pool -> pooled1), ONE dispatch
    {
        dim3 gr(11, 167, B_);
        k_mconv6<64, 4, true, true, false, true><<<gr, 256, 0, stream>>>(
            nullptr, c1wt, c1_b, idxmap, feats,
            pooled1, nullptr, L1buf,
            IDX_H, IDX_W, -1, 0, W1_, H1_, P1_H, P1_W, 64, 1);
    }
    k_finalize2<<<1, 64, 0, stream>>>(L1buf, bn1_g, bn1_b, sc1, sh1, 64,
                                      1.0f / ((float)B_ * HW1));
    {
        size_t total = (size_t)B_ * H2_ * W2_ * 8;
        k_bnrelu_pad<64><<<(unsigned)((total + 255) / 256), 256, 0, stream>>>(
            pooled1, sc1, sh1, H2_, W2_, P1_H, P1_W);
    }

    // conv2 (64->128 @333^2, raw pool -> pooled2)
    hipMemsetAsync(ws + offR2, 0, szP2, stream);
    {
        dim3 gr(6, 84, 2 * B_);
        k_mconv6<64, 4, true, true, false, false><<<gr, 256, 0, stream>>>(
            pooled1, c2wt, c2_b, nullptr, nullptr, pooled2, nullptr, L2buf,
            P1_H, P1_W, -1, 0, W2_, H2_, P2_H, P2_W, 128, 2);
    }
    k_finalize2<<<1, 128, 0, stream>>>(L2buf, bn2_g, bn2_b, sc2, sh2, 128,
                                       1.0f / ((float)B_ * HW2));
    {
        size_t total = (size_t)B_ * H3_ * W3_ * 16;
        k_bnrelu_pad<128><<<(unsigned)((total + 255) / 256), 256, 0, stream>>>(
            pooled2, sc2, sh2, H3_, W3_, P2_H, P2_W);
    }

    // h1 (128->256 @166^2, 4 out rows/block) -> h1p raw
    hipMemsetAsync(ws + offR1, 0, szH1p, stream);
    {
        dim3 gr(3, 42, 4 * B_);
        k_mconv6<128, 4, false, true, false, false><<<gr, 256, 0, stream>>>(
            pooled2, h1wt, h1_b, nullptr, nullptr, h1p, nullptr, L3buf,
            P2_H, P2_W, -1, 0, W3_, H3_, P2_H, P2_W, 256, 4);
    }
    k_finalize2<<<1, 256, 0, stream>>>(L3buf, hbn_g, hbn_b, sc3, sh3, 256,
                                       1.0f / ((float)B_ * HW3));
    {
        size_t total = (size_t)B_ * H3_ * W3_ * 32;
        k_bnrelu_pad<256><<<(unsigned)((total + 255) / 256), 256, 0, stream>>>(
            h1p, sc3, sh3, H3_, W3_, P2_H, P2_W);
    }

    // heads: fused 26-channel conv, f32 out
    {
        dim3 gr(3, 42, B_);
        k_mconv6<256, 2, false, false, true, false><<<gr, 256, 0, stream>>>(
            h1p, hdwt, hdbias, nullptr, nullptr, nullptr, (float*)d_out, nullptr,
            P2_H, P2_W, -1, 0, W3_, H3_, P2_H, P2_W, 32, 1);
    }
}